// Round 9
// baseline (372.726 us; speedup 1.0000x reference)
//
#include <hip/hip_runtime.h>

// Problem constants (x is [32,128,96,128] fp32)
#define BSZ 32
#define CC  128          // channels
#define CH  64           // C/2
#define HWN 12288        // 128*96 spatial positions
#define BPB 64           // blocks per batch for the streaming passes
#define ROWS (HWN/BPB)   // 192 rows per block

using f4 = __attribute__((ext_vector_type(4))) float;

// ---------------- Pass 1: streaming stats + last-block mid ----------------
// Per row n of batch b:  q = x_row . wq_ch ;  e = exp(q)
// Per-block partials: pS[b,blk,c]=sum e*x ; pX[b,blk,c]=sum x ; pZ[b,blk]=sum e
// The LAST block of each batch to finish (atomic ticket) computes the mid
// stage inline (no extra dispatch, no spinning, no replication):
//   S,X,Z = reduce partials ; ctxh=(S@wv_ch)/Z ; qsp=softmax((X@wq_sp)/hw)
//   ctx=ctxh@w_ch -> LN -> sigmoid -> mask_ch[b,:] ; wf[b,:]=wv_sp@qsp
__global__ __launch_bounds__(256, 8) void psa_pass1(
    const float* __restrict__ x, const float* __restrict__ wq_ch,
    const float* __restrict__ wv_ch, const float* __restrict__ w_ch,
    const float* __restrict__ gamma, const float* __restrict__ beta,
    const float* __restrict__ wq_sp, const float* __restrict__ wv_sp,
    float* __restrict__ pS, float* __restrict__ pX, float* __restrict__ pZ,
    float* __restrict__ mask_ch, float* __restrict__ wf,
    unsigned* __restrict__ counters)
{
    const int b    = blockIdx.x / BPB;
    const int blk  = blockIdx.x % BPB;
    const int tid  = threadIdx.x;
    const int l32  = tid & 31;      // lane within 32-lane row group
    const int slot = tid >> 5;      // 0..7

    const f4 wq = reinterpret_cast<const f4*>(wq_ch)[l32];

    float s0=0.f,s1=0.f,s2=0.f,s3=0.f;
    float a0=0.f,a1=0.f,a2=0.f,a3=0.f;
    float zacc=0.f;

    const float* xb = x + (size_t)b * (size_t)(HWN * CC);
    const int row0 = blk * ROWS;

    // 4 rows in flight per 32-lane slot (8 per wave)
    for (int i = slot; i < ROWS; i += 32) {
        const f4 x0 = reinterpret_cast<const f4*>(xb + (size_t)(row0 + i)      * CC)[l32];
        const f4 x1 = reinterpret_cast<const f4*>(xb + (size_t)(row0 + i + 8)  * CC)[l32];
        const f4 x2 = reinterpret_cast<const f4*>(xb + (size_t)(row0 + i + 16) * CC)[l32];
        const f4 x3 = reinterpret_cast<const f4*>(xb + (size_t)(row0 + i + 24) * CC)[l32];
        float p0 = x0.x*wq.x + x0.y*wq.y + x0.z*wq.z + x0.w*wq.w;
        float p1 = x1.x*wq.x + x1.y*wq.y + x1.z*wq.z + x1.w*wq.w;
        float p2 = x2.x*wq.x + x2.y*wq.y + x2.z*wq.z + x2.w*wq.w;
        float p3 = x3.x*wq.x + x3.y*wq.y + x3.z*wq.z + x3.w*wq.w;
        p0 += __shfl_xor(p0, 1);  p1 += __shfl_xor(p1, 1);
        p2 += __shfl_xor(p2, 1);  p3 += __shfl_xor(p3, 1);
        p0 += __shfl_xor(p0, 2);  p1 += __shfl_xor(p1, 2);
        p2 += __shfl_xor(p2, 2);  p3 += __shfl_xor(p3, 2);
        p0 += __shfl_xor(p0, 4);  p1 += __shfl_xor(p1, 4);
        p2 += __shfl_xor(p2, 4);  p3 += __shfl_xor(p3, 4);
        p0 += __shfl_xor(p0, 8);  p1 += __shfl_xor(p1, 8);
        p2 += __shfl_xor(p2, 8);  p3 += __shfl_xor(p3, 8);
        p0 += __shfl_xor(p0, 16); p1 += __shfl_xor(p1, 16);
        p2 += __shfl_xor(p2, 16); p3 += __shfl_xor(p3, 16);
        const float e0 = __expf(p0), e1 = __expf(p1);
        const float e2 = __expf(p2), e3 = __expf(p3);
        if (l32 == 0) zacc += (e0 + e1) + (e2 + e3);
        s0 += e0*x0.x + e1*x1.x + e2*x2.x + e3*x3.x;
        s1 += e0*x0.y + e1*x1.y + e2*x2.y + e3*x3.y;
        s2 += e0*x0.z + e1*x1.z + e2*x2.z + e3*x3.z;
        s3 += e0*x0.w + e1*x1.w + e2*x2.w + e3*x3.w;
        a0 += (x0.x + x1.x) + (x2.x + x3.x);
        a1 += (x0.y + x1.y) + (x2.y + x3.y);
        a2 += (x0.z + x1.z) + (x2.z + x3.z);
        a3 += (x0.w + x1.w) + (x2.w + x3.w);
    }

    __shared__ float Ssh[CC];
    __shared__ float Xsh[CC];
    __shared__ float zsh;
    if (tid < CC) { Ssh[tid] = 0.f; Xsh[tid] = 0.f; }
    if (tid == 0) zsh = 0.f;
    __syncthreads();

    const int cb = l32 * 4;
    atomicAdd(&Ssh[cb+0], s0); atomicAdd(&Ssh[cb+1], s1);
    atomicAdd(&Ssh[cb+2], s2); atomicAdd(&Ssh[cb+3], s3);
    atomicAdd(&Xsh[cb+0], a0); atomicAdd(&Xsh[cb+1], a1);
    atomicAdd(&Xsh[cb+2], a2); atomicAdd(&Xsh[cb+3], a3);
    if (l32 == 0) atomicAdd(&zsh, zacc);
    __syncthreads();

    const size_t base = (size_t)(b * BPB + blk) * CC;
    if (tid < CC) {
        pS[base + tid] = Ssh[tid];
        pX[base + tid] = Xsh[tid];
    }
    if (tid == 0) pZ[b * BPB + blk] = zsh;

    // ---- last-arriver ticket (no spinning) ----
    __syncthreads();            // drain this block's partial stores
    __threadfence();            // release: publish partials device-wide
    __shared__ unsigned lastf;
    if (tid == 0)
        lastf = (atomicAdd(&counters[b], 1u) == (unsigned)(BPB - 1)) ? 1u : 0u;
    __syncthreads();
    if (!lastf) return;
    __threadfence();            // acquire: see all 64 blocks' partials

    // ---------------- mid (only the last block per batch) ----------------
    __shared__ float ctxh[CH], qsp[CH], red2[2];

    if (tid < CC) {
        const float* pSb = pS + (size_t)b * BPB * CC;
        const float* pXb = pX + (size_t)b * BPB * CC;
        float s = 0.f, a = 0.f;
        #pragma unroll
        for (int k = 0; k < BPB; ++k) {
            s += pSb[(size_t)k * CC + tid];
            a += pXb[(size_t)k * CC + tid];
        }
        Ssh[tid] = s; Xsh[tid] = a;
    }
    if (tid < 64) {   // wave 0 reduces Z over 64 partials
        float z = pZ[b * BPB + tid];
        z += __shfl_xor(z, 1); z += __shfl_xor(z, 2);  z += __shfl_xor(z, 4);
        z += __shfl_xor(z, 8); z += __shfl_xor(z, 16); z += __shfl_xor(z, 32);
        if (tid == 0) zsh = z;
    }
    __syncthreads();

    if (tid < CH) {
        float a = 0.f, aq = 0.f;
        #pragma unroll
        for (int c = 0; c < CC; ++c) {
            a  += Ssh[c] * wv_ch[c*CH + tid];
            aq += Xsh[c] * wq_sp[c*CH + tid];
        }
        ctxh[tid] = a / zsh;
        // spatial softmax over 64 (wave 0)
        float q = aq * (1.0f / (float)HWN);
        float m = q;
        m = fmaxf(m, __shfl_xor(m, 1));  m = fmaxf(m, __shfl_xor(m, 2));
        m = fmaxf(m, __shfl_xor(m, 4));  m = fmaxf(m, __shfl_xor(m, 8));
        m = fmaxf(m, __shfl_xor(m, 16)); m = fmaxf(m, __shfl_xor(m, 32));
        float e = __expf(q - m);
        float sum = e;
        sum += __shfl_xor(sum, 1);  sum += __shfl_xor(sum, 2);
        sum += __shfl_xor(sum, 4);  sum += __shfl_xor(sum, 8);
        sum += __shfl_xor(sum, 16); sum += __shfl_xor(sum, 32);
        qsp[tid] = e / sum;
    }
    __syncthreads();

    float ctx = 0.f;
    if (tid < CC) {
        #pragma unroll
        for (int d = 0; d < CH; ++d) ctx += ctxh[d] * w_ch[d*CC + tid];
    }
    {
        float r = (tid < CC) ? ctx : 0.f;
        r += __shfl_xor(r, 1);  r += __shfl_xor(r, 2);  r += __shfl_xor(r, 4);
        r += __shfl_xor(r, 8);  r += __shfl_xor(r, 16); r += __shfl_xor(r, 32);
        if ((tid & 63) == 0 && tid < CC) red2[tid >> 6] = r;
    }
    __syncthreads();
    const float mu = (red2[0] + red2[1]) * (1.0f / CC);
    __syncthreads();
    const float dc = (tid < CC) ? (ctx - mu) : 0.f;
    {
        float r = dc * dc;
        r += __shfl_xor(r, 1);  r += __shfl_xor(r, 2);  r += __shfl_xor(r, 4);
        r += __shfl_xor(r, 8);  r += __shfl_xor(r, 16); r += __shfl_xor(r, 32);
        if ((tid & 63) == 0 && tid < CC) red2[tid >> 6] = r;
    }
    __syncthreads();
    const float var = (red2[0] + red2[1]) * (1.0f / CC);

    if (tid < CC) {
        const float nrm = dc * rsqrtf(var + 1e-5f) * gamma[tid] + beta[tid];
        mask_ch[b*CC + tid] = 1.0f / (1.0f + __expf(-nrm));
        float wacc = 0.f;
        #pragma unroll
        for (int d = 0; d < CH; ++d) wacc += wv_sp[tid*CH + d] * qsp[d];
        wf[b*CC + tid] = wacc;
    }
}

// ---------------- Pass 2: streaming output (identical to R6) ----------------
// out[b,n,c] = x[b,n,c] * (mask_ch[b,c] + sigmoid(x_row . wf[b,:]))
// 6 rows in flight per 32-lane slot; nt stores protect L3-resident x.
__global__ __launch_bounds__(256, 6) void psa_pass2(
    const float* __restrict__ x, const float* __restrict__ mask_ch,
    const float* __restrict__ wf, float* __restrict__ out)
{
    const int b    = blockIdx.x / BPB;
    const int blk  = blockIdx.x % BPB;
    const int tid  = threadIdx.x;
    const int l32  = tid & 31;
    const int slot = tid >> 5;

    const f4 m4 = reinterpret_cast<const f4*>(mask_ch + b*CC)[l32];
    const f4 w4 = reinterpret_cast<const f4*>(wf + b*CC)[l32];

    const float* xb = x   + (size_t)b * (size_t)(HWN * CC);
    float*       ob = out + (size_t)b * (size_t)(HWN * CC);
    const int row0 = blk * ROWS;

    // ROWS=192 = 4 iterations of 48-row stride, 6 rows in flight per slot
    for (int i = slot; i < ROWS; i += 48) {
        const size_t off0 = (size_t)(row0 + i)      * CC;
        const size_t off1 = (size_t)(row0 + i + 8)  * CC;
        const size_t off2 = (size_t)(row0 + i + 16) * CC;
        const size_t off3 = (size_t)(row0 + i + 24) * CC;
        const size_t off4 = (size_t)(row0 + i + 32) * CC;
        const size_t off5 = (size_t)(row0 + i + 40) * CC;
        const f4 x0 = reinterpret_cast<const f4*>(xb + off0)[l32];
        const f4 x1 = reinterpret_cast<const f4*>(xb + off1)[l32];
        const f4 x2 = reinterpret_cast<const f4*>(xb + off2)[l32];
        const f4 x3 = reinterpret_cast<const f4*>(xb + off3)[l32];
        const f4 x4 = reinterpret_cast<const f4*>(xb + off4)[l32];
        const f4 x5 = reinterpret_cast<const f4*>(xb + off5)[l32];
        float p0 = x0.x*w4.x + x0.y*w4.y + x0.z*w4.z + x0.w*w4.w;
        float p1 = x1.x*w4.x + x1.y*w4.y + x1.z*w4.z + x1.w*w4.w;
        float p2 = x2.x*w4.x + x2.y*w4.y + x2.z*w4.z + x2.w*w4.w;
        float p3 = x3.x*w4.x + x3.y*w4.y + x3.z*w4.z + x3.w*w4.w;
        float p4 = x4.x*w4.x + x4.y*w4.y + x4.z*w4.z + x4.w*w4.w;
        float p5 = x5.x*w4.x + x5.y*w4.y + x5.z*w4.z + x5.w*w4.w;
        p0 += __shfl_xor(p0, 1);  p1 += __shfl_xor(p1, 1);  p2 += __shfl_xor(p2, 1);
        p3 += __shfl_xor(p3, 1);  p4 += __shfl_xor(p4, 1);  p5 += __shfl_xor(p5, 1);
        p0 += __shfl_xor(p0, 2);  p1 += __shfl_xor(p1, 2);  p2 += __shfl_xor(p2, 2);
        p3 += __shfl_xor(p3, 2);  p4 += __shfl_xor(p4, 2);  p5 += __shfl_xor(p5, 2);
        p0 += __shfl_xor(p0, 4);  p1 += __shfl_xor(p1, 4);  p2 += __shfl_xor(p2, 4);
        p3 += __shfl_xor(p3, 4);  p4 += __shfl_xor(p4, 4);  p5 += __shfl_xor(p5, 4);
        p0 += __shfl_xor(p0, 8);  p1 += __shfl_xor(p1, 8);  p2 += __shfl_xor(p2, 8);
        p3 += __shfl_xor(p3, 8);  p4 += __shfl_xor(p4, 8);  p5 += __shfl_xor(p5, 8);
        p0 += __shfl_xor(p0, 16); p1 += __shfl_xor(p1, 16); p2 += __shfl_xor(p2, 16);
        p3 += __shfl_xor(p3, 16); p4 += __shfl_xor(p4, 16); p5 += __shfl_xor(p5, 16);
        const float g0 = 1.0f / (1.0f + __expf(-p0));
        const float g1 = 1.0f / (1.0f + __expf(-p1));
        const float g2 = 1.0f / (1.0f + __expf(-p2));
        const float g3 = 1.0f / (1.0f + __expf(-p3));
        const float g4 = 1.0f / (1.0f + __expf(-p4));
        const float g5 = 1.0f / (1.0f + __expf(-p5));
        f4 o0, o1, o2, o3, o4, o5;
        o0.x = x0.x*(m4.x+g0); o0.y = x0.y*(m4.y+g0); o0.z = x0.z*(m4.z+g0); o0.w = x0.w*(m4.w+g0);
        o1.x = x1.x*(m4.x+g1); o1.y = x1.y*(m4.y+g1); o1.z = x1.z*(m4.z+g1); o1.w = x1.w*(m4.w+g1);
        o2.x = x2.x*(m4.x+g2); o2.y = x2.y*(m4.y+g2); o2.z = x2.z*(m4.z+g2); o2.w = x2.w*(m4.w+g2);
        o3.x = x3.x*(m4.x+g3); o3.y = x3.y*(m4.y+g3); o3.z = x3.z*(m4.z+g3); o3.w = x3.w*(m4.w+g3);
        o4.x = x4.x*(m4.x+g4); o4.y = x4.y*(m4.y+g4); o4.z = x4.z*(m4.z+g4); o4.w = x4.w*(m4.w+g4);
        o5.x = x5.x*(m4.x+g5); o5.y = x5.y*(m4.y+g5); o5.z = x5.z*(m4.z+g5); o5.w = x5.w*(m4.w+g5);
        // non-temporal: keep the out stream from evicting x in cache (R8 A/B: -20us)
        __builtin_nontemporal_store(o0, reinterpret_cast<f4*>(ob + off0) + l32);
        __builtin_nontemporal_store(o1, reinterpret_cast<f4*>(ob + off1) + l32);
        __builtin_nontemporal_store(o2, reinterpret_cast<f4*>(ob + off2) + l32);
        __builtin_nontemporal_store(o3, reinterpret_cast<f4*>(ob + off3) + l32);
        __builtin_nontemporal_store(o4, reinterpret_cast<f4*>(ob + off4) + l32);
        __builtin_nontemporal_store(o5, reinterpret_cast<f4*>(ob + off5) + l32);
    }
}

extern "C" void kernel_launch(void* const* d_in, const int* in_sizes, int n_in,
                              void* d_out, int out_size, void* d_ws, size_t ws_size,
                              hipStream_t stream) {
    const float* x     = (const float*)d_in[0];
    const float* wq_ch = (const float*)d_in[1];
    const float* wv_ch = (const float*)d_in[2];
    const float* w_ch  = (const float*)d_in[3];
    const float* gamma = (const float*)d_in[4];
    const float* beta  = (const float*)d_in[5];
    const float* wq_sp = (const float*)d_in[6];
    const float* wv_sp = (const float*)d_in[7];
    float* out = (float*)d_out;

    // workspace (floats): pS[32*64*128] | pX[32*64*128] | pZ[32*64]
    //                   | mask[32*128] | wf[32*128] | counters[32]
    float* ws   = (float*)d_ws;
    float* pS   = ws;
    float* pX   = pS + (size_t)BSZ*BPB*CC;
    float* pZ   = pX + (size_t)BSZ*BPB*CC;
    float* mask = pZ + BSZ*BPB;
    float* wf   = mask + BSZ*CC;
    unsigned* counters = (unsigned*)(wf + BSZ*CC);

    // zero the per-batch arrival tickets (128 B, stream-ordered)
    hipMemsetAsync((void*)counters, 0, BSZ * sizeof(unsigned), stream);

    psa_pass1<<<BSZ*BPB, 256, 0, stream>>>(x, wq_ch, wv_ch, w_ch, gamma, beta,
                                           wq_sp, wv_sp, pS, pX, pZ,
                                           mask, wf, counters);
    psa_pass2<<<BSZ*BPB, 256, 0, stream>>>(x, mask, wf, out);
}

// Round 10
// 132.918 us; speedup vs baseline: 2.8042x; 2.8042x over previous
//
#include <hip/hip_runtime.h>

// Problem constants (x is [32,128,96,128] fp32)
#define BSZ 32
#define CC  128          // channels
#define CH  64           // C/2
#define HWN 12288        // 128*96 spatial positions
#define BPB 64           // blocks per batch for the streaming passes
#define ROWS (HWN/BPB)   // 192 rows per block

using f4 = __attribute__((ext_vector_type(4))) float;

// ---------------- Pass 1: streaming stats + fence-free last-block mid -------
// Per row n of batch b:  q = x_row . wq_ch ;  e = exp(q)
// Block totals go STRAIGHT to device-scope atomicAdd accumulators
// S[b,c], X[b,c], Z[b] (coherent point, no per-XCD L2 staleness, NO fences --
// R9 showed per-block __threadfence serializes the fabric, +330us).
// __syncthreads() drains the atomics (vmcnt) before the ticket; the 64th
// arriver computes the mid stage inline and writes mask_ch[b,:], wf[b,:].
__global__ __launch_bounds__(256, 8) void psa_pass1(
    const float* __restrict__ x, const float* __restrict__ wq_ch,
    const float* __restrict__ wv_ch, const float* __restrict__ w_ch,
    const float* __restrict__ gamma, const float* __restrict__ beta,
    const float* __restrict__ wq_sp, const float* __restrict__ wv_sp,
    float* __restrict__ S, float* __restrict__ Xg, float* __restrict__ Z,
    float* __restrict__ mask_ch, float* __restrict__ wf,
    unsigned* __restrict__ counters)
{
    const int b    = blockIdx.x / BPB;
    const int blk  = blockIdx.x % BPB;
    const int tid  = threadIdx.x;
    const int l32  = tid & 31;      // lane within 32-lane row group
    const int slot = tid >> 5;      // 0..7

    const f4 wq = reinterpret_cast<const f4*>(wq_ch)[l32];

    float s0=0.f,s1=0.f,s2=0.f,s3=0.f;
    float a0=0.f,a1=0.f,a2=0.f,a3=0.f;
    float zacc=0.f;

    const float* xb = x + (size_t)b * (size_t)(HWN * CC);
    const int row0 = blk * ROWS;

    // 4 rows in flight per 32-lane slot (8 per wave)
    for (int i = slot; i < ROWS; i += 32) {
        const f4 x0 = reinterpret_cast<const f4*>(xb + (size_t)(row0 + i)      * CC)[l32];
        const f4 x1 = reinterpret_cast<const f4*>(xb + (size_t)(row0 + i + 8)  * CC)[l32];
        const f4 x2 = reinterpret_cast<const f4*>(xb + (size_t)(row0 + i + 16) * CC)[l32];
        const f4 x3 = reinterpret_cast<const f4*>(xb + (size_t)(row0 + i + 24) * CC)[l32];
        float p0 = x0.x*wq.x + x0.y*wq.y + x0.z*wq.z + x0.w*wq.w;
        float p1 = x1.x*wq.x + x1.y*wq.y + x1.z*wq.z + x1.w*wq.w;
        float p2 = x2.x*wq.x + x2.y*wq.y + x2.z*wq.z + x2.w*wq.w;
        float p3 = x3.x*wq.x + x3.y*wq.y + x3.z*wq.z + x3.w*wq.w;
        p0 += __shfl_xor(p0, 1);  p1 += __shfl_xor(p1, 1);
        p2 += __shfl_xor(p2, 1);  p3 += __shfl_xor(p3, 1);
        p0 += __shfl_xor(p0, 2);  p1 += __shfl_xor(p1, 2);
        p2 += __shfl_xor(p2, 2);  p3 += __shfl_xor(p3, 2);
        p0 += __shfl_xor(p0, 4);  p1 += __shfl_xor(p1, 4);
        p2 += __shfl_xor(p2, 4);  p3 += __shfl_xor(p3, 4);
        p0 += __shfl_xor(p0, 8);  p1 += __shfl_xor(p1, 8);
        p2 += __shfl_xor(p2, 8);  p3 += __shfl_xor(p3, 8);
        p0 += __shfl_xor(p0, 16); p1 += __shfl_xor(p1, 16);
        p2 += __shfl_xor(p2, 16); p3 += __shfl_xor(p3, 16);
        const float e0 = __expf(p0), e1 = __expf(p1);
        const float e2 = __expf(p2), e3 = __expf(p3);
        if (l32 == 0) zacc += (e0 + e1) + (e2 + e3);
        s0 += e0*x0.x + e1*x1.x + e2*x2.x + e3*x3.x;
        s1 += e0*x0.y + e1*x1.y + e2*x2.y + e3*x3.y;
        s2 += e0*x0.z + e1*x1.z + e2*x2.z + e3*x3.z;
        s3 += e0*x0.w + e1*x1.w + e2*x2.w + e3*x3.w;
        a0 += (x0.x + x1.x) + (x2.x + x3.x);
        a1 += (x0.y + x1.y) + (x2.y + x3.y);
        a2 += (x0.z + x1.z) + (x2.z + x3.z);
        a3 += (x0.w + x1.w) + (x2.w + x3.w);
    }

    __shared__ float Ssh[CC];
    __shared__ float Xsh[CC];
    __shared__ float zsh;
    if (tid < CC) { Ssh[tid] = 0.f; Xsh[tid] = 0.f; }
    if (tid == 0) zsh = 0.f;
    __syncthreads();

    const int cb = l32 * 4;
    atomicAdd(&Ssh[cb+0], s0); atomicAdd(&Ssh[cb+1], s1);
    atomicAdd(&Ssh[cb+2], s2); atomicAdd(&Ssh[cb+3], s3);
    atomicAdd(&Xsh[cb+0], a0); atomicAdd(&Xsh[cb+1], a1);
    atomicAdd(&Xsh[cb+2], a2); atomicAdd(&Xsh[cb+3], a3);
    if (l32 == 0) atomicAdd(&zsh, zacc);
    __syncthreads();

    // device-scope accumulation at the coherent point (no fences needed)
    if (tid < CC) {
        atomicAdd(&S[b*CC + tid],  Ssh[tid]);
        atomicAdd(&Xg[b*CC + tid], Xsh[tid]);
    }
    if (tid == 0) atomicAdd(&Z[b], zsh);

    // ticket: syncthreads drains this block's atomics (vmcnt) first
    __syncthreads();
    __shared__ unsigned lastf;
    if (tid == 0)
        lastf = (atomicAdd(&counters[b], 1u) == (unsigned)(BPB - 1)) ? 1u : 0u;
    __syncthreads();
    if (!lastf) return;

    // ---------------- mid (64th arriver only; totals are complete) ----------
    __shared__ float ctxh[CH], qsp[CH], red2[2];

    if (tid < CC) {
        Ssh[tid] = __hip_atomic_load(&S[b*CC + tid],  __ATOMIC_RELAXED,
                                     __HIP_MEMORY_SCOPE_AGENT);
        Xsh[tid] = __hip_atomic_load(&Xg[b*CC + tid], __ATOMIC_RELAXED,
                                     __HIP_MEMORY_SCOPE_AGENT);
    }
    if (tid == 0)
        zsh = __hip_atomic_load(&Z[b], __ATOMIC_RELAXED,
                                __HIP_MEMORY_SCOPE_AGENT);
    __syncthreads();

    if (tid < CH) {
        float a = 0.f, aq = 0.f;
        #pragma unroll
        for (int c = 0; c < CC; ++c) {
            a  += Ssh[c] * wv_ch[c*CH + tid];
            aq += Xsh[c] * wq_sp[c*CH + tid];
        }
        ctxh[tid] = a / zsh;
        // spatial softmax over 64 (wave 0)
        float q = aq * (1.0f / (float)HWN);
        float m = q;
        m = fmaxf(m, __shfl_xor(m, 1));  m = fmaxf(m, __shfl_xor(m, 2));
        m = fmaxf(m, __shfl_xor(m, 4));  m = fmaxf(m, __shfl_xor(m, 8));
        m = fmaxf(m, __shfl_xor(m, 16)); m = fmaxf(m, __shfl_xor(m, 32));
        float e = __expf(q - m);
        float sum = e;
        sum += __shfl_xor(sum, 1);  sum += __shfl_xor(sum, 2);
        sum += __shfl_xor(sum, 4);  sum += __shfl_xor(sum, 8);
        sum += __shfl_xor(sum, 16); sum += __shfl_xor(sum, 32);
        qsp[tid] = e / sum;
    }
    __syncthreads();

    float ctx = 0.f;
    if (tid < CC) {
        #pragma unroll
        for (int d = 0; d < CH; ++d) ctx += ctxh[d] * w_ch[d*CC + tid];
    }
    {
        float r = (tid < CC) ? ctx : 0.f;
        r += __shfl_xor(r, 1);  r += __shfl_xor(r, 2);  r += __shfl_xor(r, 4);
        r += __shfl_xor(r, 8);  r += __shfl_xor(r, 16); r += __shfl_xor(r, 32);
        if ((tid & 63) == 0 && tid < CC) red2[tid >> 6] = r;
    }
    __syncthreads();
    const float mu = (red2[0] + red2[1]) * (1.0f / CC);
    __syncthreads();
    const float dc = (tid < CC) ? (ctx - mu) : 0.f;
    {
        float r = dc * dc;
        r += __shfl_xor(r, 1);  r += __shfl_xor(r, 2);  r += __shfl_xor(r, 4);
        r += __shfl_xor(r, 8);  r += __shfl_xor(r, 16); r += __shfl_xor(r, 32);
        if ((tid & 63) == 0 && tid < CC) red2[tid >> 6] = r;
    }
    __syncthreads();
    const float var = (red2[0] + red2[1]) * (1.0f / CC);

    if (tid < CC) {
        const float nrm = dc * rsqrtf(var + 1e-5f) * gamma[tid] + beta[tid];
        mask_ch[b*CC + tid] = 1.0f / (1.0f + __expf(-nrm));
        float wacc = 0.f;
        #pragma unroll
        for (int d = 0; d < CH; ++d) wacc += wv_sp[tid*CH + d] * qsp[d];
        wf[b*CC + tid] = wacc;
    }
}

// ---------------- Pass 2: streaming output (identical to R6 best) -----------
// out[b,n,c] = x[b,n,c] * (mask_ch[b,c] + sigmoid(x_row . wf[b,:]))
__global__ __launch_bounds__(256, 6) void psa_pass2(
    const float* __restrict__ x, const float* __restrict__ mask_ch,
    const float* __restrict__ wf, float* __restrict__ out)
{
    const int b    = blockIdx.x / BPB;
    const int blk  = blockIdx.x % BPB;
    const int tid  = threadIdx.x;
    const int l32  = tid & 31;
    const int slot = tid >> 5;

    const f4 m4 = reinterpret_cast<const f4*>(mask_ch + b*CC)[l32];
    const f4 w4 = reinterpret_cast<const f4*>(wf + b*CC)[l32];

    const float* xb = x   + (size_t)b * (size_t)(HWN * CC);
    float*       ob = out + (size_t)b * (size_t)(HWN * CC);
    const int row0 = blk * ROWS;

    // ROWS=192 = 4 iterations of 48-row stride, 6 rows in flight per slot
    for (int i = slot; i < ROWS; i += 48) {
        const size_t off0 = (size_t)(row0 + i)      * CC;
        const size_t off1 = (size_t)(row0 + i + 8)  * CC;
        const size_t off2 = (size_t)(row0 + i + 16) * CC;
        const size_t off3 = (size_t)(row0 + i + 24) * CC;
        const size_t off4 = (size_t)(row0 + i + 32) * CC;
        const size_t off5 = (size_t)(row0 + i + 40) * CC;
        const f4 x0 = reinterpret_cast<const f4*>(xb + off0)[l32];
        const f4 x1 = reinterpret_cast<const f4*>(xb + off1)[l32];
        const f4 x2 = reinterpret_cast<const f4*>(xb + off2)[l32];
        const f4 x3 = reinterpret_cast<const f4*>(xb + off3)[l32];
        const f4 x4 = reinterpret_cast<const f4*>(xb + off4)[l32];
        const f4 x5 = reinterpret_cast<const f4*>(xb + off5)[l32];
        float p0 = x0.x*w4.x + x0.y*w4.y + x0.z*w4.z + x0.w*w4.w;
        float p1 = x1.x*w4.x + x1.y*w4.y + x1.z*w4.z + x1.w*w4.w;
        float p2 = x2.x*w4.x + x2.y*w4.y + x2.z*w4.z + x2.w*w4.w;
        float p3 = x3.x*w4.x + x3.y*w4.y + x3.z*w4.z + x3.w*w4.w;
        float p4 = x4.x*w4.x + x4.y*w4.y + x4.z*w4.z + x4.w*w4.w;
        float p5 = x5.x*w4.x + x5.y*w4.y + x5.z*w4.z + x5.w*w4.w;
        p0 += __shfl_xor(p0, 1);  p1 += __shfl_xor(p1, 1);  p2 += __shfl_xor(p2, 1);
        p3 += __shfl_xor(p3, 1);  p4 += __shfl_xor(p4, 1);  p5 += __shfl_xor(p5, 1);
        p0 += __shfl_xor(p0, 2);  p1 += __shfl_xor(p1, 2);  p2 += __shfl_xor(p2, 2);
        p3 += __shfl_xor(p3, 2);  p4 += __shfl_xor(p4, 2);  p5 += __shfl_xor(p5, 2);
        p0 += __shfl_xor(p0, 4);  p1 += __shfl_xor(p1, 4);  p2 += __shfl_xor(p2, 4);
        p3 += __shfl_xor(p3, 4);  p4 += __shfl_xor(p4, 4);  p5 += __shfl_xor(p5, 4);
        p0 += __shfl_xor(p0, 8);  p1 += __shfl_xor(p1, 8);  p2 += __shfl_xor(p2, 8);
        p3 += __shfl_xor(p3, 8);  p4 += __shfl_xor(p4, 8);  p5 += __shfl_xor(p5, 8);
        p0 += __shfl_xor(p0, 16); p1 += __shfl_xor(p1, 16); p2 += __shfl_xor(p2, 16);
        p3 += __shfl_xor(p3, 16); p4 += __shfl_xor(p4, 16); p5 += __shfl_xor(p5, 16);
        const float g0 = 1.0f / (1.0f + __expf(-p0));
        const float g1 = 1.0f / (1.0f + __expf(-p1));
        const float g2 = 1.0f / (1.0f + __expf(-p2));
        const float g3 = 1.0f / (1.0f + __expf(-p3));
        const float g4 = 1.0f / (1.0f + __expf(-p4));
        const float g5 = 1.0f / (1.0f + __expf(-p5));
        f4 o0, o1, o2, o3, o4, o5;
        o0.x = x0.x*(m4.x+g0); o0.y = x0.y*(m4.y+g0); o0.z = x0.z*(m4.z+g0); o0.w = x0.w*(m4.w+g0);
        o1.x = x1.x*(m4.x+g1); o1.y = x1.y*(m4.y+g1); o1.z = x1.z*(m4.z+g1); o1.w = x1.w*(m4.w+g1);
        o2.x = x2.x*(m4.x+g2); o2.y = x2.y*(m4.y+g2); o2.z = x2.z*(m4.z+g2); o2.w = x2.w*(m4.w+g2);
        o3.x = x3.x*(m4.x+g3); o3.y = x3.y*(m4.y+g3); o3.z = x3.z*(m4.z+g3); o3.w = x3.w*(m4.w+g3);
        o4.x = x4.x*(m4.x+g4); o4.y = x4.y*(m4.y+g4); o4.z = x4.z*(m4.z+g4); o4.w = x4.w*(m4.w+g4);
        o5.x = x5.x*(m4.x+g5); o5.y = x5.y*(m4.y+g5); o5.z = x5.z*(m4.z+g5); o5.w = x5.w*(m4.w+g5);
        // non-temporal: keep the out stream from evicting x in cache (R8 A/B: -20us)
        __builtin_nontemporal_store(o0, reinterpret_cast<f4*>(ob + off0) + l32);
        __builtin_nontemporal_store(o1, reinterpret_cast<f4*>(ob + off1) + l32);
        __builtin_nontemporal_store(o2, reinterpret_cast<f4*>(ob + off2) + l32);
        __builtin_nontemporal_store(o3, reinterpret_cast<f4*>(ob + off3) + l32);
        __builtin_nontemporal_store(o4, reinterpret_cast<f4*>(ob + off4) + l32);
        __builtin_nontemporal_store(o5, reinterpret_cast<f4*>(ob + off5) + l32);
    }
}

extern "C" void kernel_launch(void* const* d_in, const int* in_sizes, int n_in,
                              void* d_out, int out_size, void* d_ws, size_t ws_size,
                              hipStream_t stream) {
    const float* x     = (const float*)d_in[0];
    const float* wq_ch = (const float*)d_in[1];
    const float* wv_ch = (const float*)d_in[2];
    const float* w_ch  = (const float*)d_in[3];
    const float* gamma = (const float*)d_in[4];
    const float* beta  = (const float*)d_in[5];
    const float* wq_sp = (const float*)d_in[6];
    const float* wv_sp = (const float*)d_in[7];
    float* out = (float*)d_out;

    // workspace (floats): S[32*128] | X[32*128] | Z[32] | counters[32]
    //                   | mask[32*128] | wf[32*128]
    float* ws = (float*)d_ws;
    float* S  = ws;
    float* Xg = S + BSZ*CC;
    float* Z  = Xg + BSZ*CC;
    unsigned* counters = (unsigned*)(Z + BSZ);
    float* mask = (float*)(counters + BSZ);
    float* wf   = mask + BSZ*CC;

    // zero accumulators + tickets (33 KB, stream-ordered, graph-safe)
    hipMemsetAsync((void*)S, 0, (size_t)(2*BSZ*CC + 2*BSZ) * sizeof(float), stream);

    psa_pass1<<<BSZ*BPB, 256, 0, stream>>>(x, wq_ch, wv_ch, w_ch, gamma, beta,
                                           wq_sp, wv_sp, S, Xg, Z,
                                           mask, wf, counters);
    psa_pass2<<<BSZ*BPB, 256, 0, stream>>>(x, mask, wf, out);
}

// Round 11
// 118.547 us; speedup vs baseline: 3.1441x; 1.1212x over previous
//
#include <hip/hip_runtime.h>

// Problem constants (x is [32,128,96,128] fp32)
#define BSZ 32
#define CC  128          // channels
#define CH  64           // C/2
#define HWN 12288        // 128*96 spatial positions
#define BPB 64           // blocks per batch for the streaming passes
#define ROWS (HWN/BPB)   // 192 rows per block

using f4 = __attribute__((ext_vector_type(4))) float;

// R6 configuration == best measured (118.6 us). Ledger:
//  - nt stores in pass2: -19.5us vs regular (R8 A/B) -- protect L3-resident x
//  - separate tiny mid dispatch beats ALL fusion variants (R7/R9/R10)
//  - ILP/occupancy beyond this: neutral (R5/R6)

// ---------------- Pass 1: streaming stats over x ----------------
__global__ __launch_bounds__(256, 8) void psa_pass1(
    const float* __restrict__ x, const float* __restrict__ wq_ch,
    float* __restrict__ pS, float* __restrict__ pX, float* __restrict__ pZ)
{
    const int b    = blockIdx.x / BPB;
    const int blk  = blockIdx.x % BPB;
    const int tid  = threadIdx.x;
    const int l32  = tid & 31;      // lane within 32-lane row group
    const int slot = tid >> 5;      // 0..7

    const f4 wq = reinterpret_cast<const f4*>(wq_ch)[l32];

    float s0=0.f,s1=0.f,s2=0.f,s3=0.f;
    float a0=0.f,a1=0.f,a2=0.f,a3=0.f;
    float zacc=0.f;

    const float* xb = x + (size_t)b * (size_t)(HWN * CC);
    const int row0 = blk * ROWS;

    // 4 rows in flight per 32-lane slot (8 per wave)
    for (int i = slot; i < ROWS; i += 32) {
        const f4 x0 = reinterpret_cast<const f4*>(xb + (size_t)(row0 + i)      * CC)[l32];
        const f4 x1 = reinterpret_cast<const f4*>(xb + (size_t)(row0 + i + 8)  * CC)[l32];
        const f4 x2 = reinterpret_cast<const f4*>(xb + (size_t)(row0 + i + 16) * CC)[l32];
        const f4 x3 = reinterpret_cast<const f4*>(xb + (size_t)(row0 + i + 24) * CC)[l32];
        float p0 = x0.x*wq.x + x0.y*wq.y + x0.z*wq.z + x0.w*wq.w;
        float p1 = x1.x*wq.x + x1.y*wq.y + x1.z*wq.z + x1.w*wq.w;
        float p2 = x2.x*wq.x + x2.y*wq.y + x2.z*wq.z + x2.w*wq.w;
        float p3 = x3.x*wq.x + x3.y*wq.y + x3.z*wq.z + x3.w*wq.w;
        p0 += __shfl_xor(p0, 1);  p1 += __shfl_xor(p1, 1);
        p2 += __shfl_xor(p2, 1);  p3 += __shfl_xor(p3, 1);
        p0 += __shfl_xor(p0, 2);  p1 += __shfl_xor(p1, 2);
        p2 += __shfl_xor(p2, 2);  p3 += __shfl_xor(p3, 2);
        p0 += __shfl_xor(p0, 4);  p1 += __shfl_xor(p1, 4);
        p2 += __shfl_xor(p2, 4);  p3 += __shfl_xor(p3, 4);
        p0 += __shfl_xor(p0, 8);  p1 += __shfl_xor(p1, 8);
        p2 += __shfl_xor(p2, 8);  p3 += __shfl_xor(p3, 8);
        p0 += __shfl_xor(p0, 16); p1 += __shfl_xor(p1, 16);
        p2 += __shfl_xor(p2, 16); p3 += __shfl_xor(p3, 16);
        const float e0 = __expf(p0), e1 = __expf(p1);
        const float e2 = __expf(p2), e3 = __expf(p3);
        if (l32 == 0) zacc += (e0 + e1) + (e2 + e3);
        s0 += e0*x0.x + e1*x1.x + e2*x2.x + e3*x3.x;
        s1 += e0*x0.y + e1*x1.y + e2*x2.y + e3*x3.y;
        s2 += e0*x0.z + e1*x1.z + e2*x2.z + e3*x3.z;
        s3 += e0*x0.w + e1*x1.w + e2*x2.w + e3*x3.w;
        a0 += (x0.x + x1.x) + (x2.x + x3.x);
        a1 += (x0.y + x1.y) + (x2.y + x3.y);
        a2 += (x0.z + x1.z) + (x2.z + x3.z);
        a3 += (x0.w + x1.w) + (x2.w + x3.w);
    }

    __shared__ float Ssh[CC];
    __shared__ float Xsh[CC];
    __shared__ float zsh;
    if (tid < CC) { Ssh[tid] = 0.f; Xsh[tid] = 0.f; }
    if (tid == 0) zsh = 0.f;
    __syncthreads();

    const int cb = l32 * 4;
    atomicAdd(&Ssh[cb+0], s0); atomicAdd(&Ssh[cb+1], s1);
    atomicAdd(&Ssh[cb+2], s2); atomicAdd(&Ssh[cb+3], s3);
    atomicAdd(&Xsh[cb+0], a0); atomicAdd(&Xsh[cb+1], a1);
    atomicAdd(&Xsh[cb+2], a2); atomicAdd(&Xsh[cb+3], a3);
    if (l32 == 0) atomicAdd(&zsh, zacc);
    __syncthreads();

    const size_t base = (size_t)(b * BPB + blk) * CC;
    if (tid < CC) {
        pS[base + tid] = Ssh[tid];
        pX[base + tid] = Xsh[tid];
    }
    if (tid == 0) pZ[b * BPB + blk] = zsh;
}

// ---------------- Mid: tiny per-batch kernel (32 blocks x 128 threads) ------
__global__ __launch_bounds__(128) void psa_mid(
    const float* __restrict__ pS, const float* __restrict__ pX,
    const float* __restrict__ pZ,
    const float* __restrict__ wv_ch, const float* __restrict__ w_ch,
    const float* __restrict__ gamma, const float* __restrict__ beta,
    const float* __restrict__ wq_sp, const float* __restrict__ wv_sp,
    float* __restrict__ mask_ch, float* __restrict__ wf)
{
    const int b = blockIdx.x;
    const int t = threadIdx.x;   // 0..127

    __shared__ float Ssh[CC], Xsh[CC], ctxh[CH], qsp[CH], zsh, red2[2];

    {
        const float* pSb = pS + (size_t)b * BPB * CC;
        const float* pXb = pX + (size_t)b * BPB * CC;
        float s = 0.f, a = 0.f;
        #pragma unroll
        for (int k = 0; k < BPB; ++k) {
            s += pSb[(size_t)k * CC + t];
            a += pXb[(size_t)k * CC + t];
        }
        Ssh[t] = s; Xsh[t] = a;
    }
    if (t < 64) {   // wave 0 reduces Z over 64 partials
        float z = pZ[b * BPB + t];
        z += __shfl_xor(z, 1); z += __shfl_xor(z, 2);  z += __shfl_xor(z, 4);
        z += __shfl_xor(z, 8); z += __shfl_xor(z, 16); z += __shfl_xor(z, 32);
        if (t == 0) zsh = z;
    }
    __syncthreads();

    if (t < CH) {
        float a = 0.f, aq = 0.f;
        #pragma unroll
        for (int c = 0; c < CC; ++c) {
            a  += Ssh[c] * wv_ch[c*CH + t];
            aq += Xsh[c] * wq_sp[c*CH + t];
        }
        ctxh[t] = a / zsh;
        // spatial softmax over 64 (wave 0)
        float q = aq * (1.0f / (float)HWN);
        float m = q;
        m = fmaxf(m, __shfl_xor(m, 1));  m = fmaxf(m, __shfl_xor(m, 2));
        m = fmaxf(m, __shfl_xor(m, 4));  m = fmaxf(m, __shfl_xor(m, 8));
        m = fmaxf(m, __shfl_xor(m, 16)); m = fmaxf(m, __shfl_xor(m, 32));
        float e = __expf(q - m);
        float sum = e;
        sum += __shfl_xor(sum, 1);  sum += __shfl_xor(sum, 2);
        sum += __shfl_xor(sum, 4);  sum += __shfl_xor(sum, 8);
        sum += __shfl_xor(sum, 16); sum += __shfl_xor(sum, 32);
        qsp[t] = e / sum;
    }
    __syncthreads();

    float ctx = 0.f;
    #pragma unroll
    for (int d = 0; d < CH; ++d) ctx += ctxh[d] * w_ch[d*CC + t];

    const int wid = t >> 6;
    {
        float r = ctx;
        r += __shfl_xor(r, 1);  r += __shfl_xor(r, 2);  r += __shfl_xor(r, 4);
        r += __shfl_xor(r, 8);  r += __shfl_xor(r, 16); r += __shfl_xor(r, 32);
        if ((t & 63) == 0) red2[wid] = r;
    }
    __syncthreads();
    const float mu = (red2[0] + red2[1]) * (1.0f / CC);
    __syncthreads();
    const float dc = ctx - mu;
    {
        float r = dc * dc;
        r += __shfl_xor(r, 1);  r += __shfl_xor(r, 2);  r += __shfl_xor(r, 4);
        r += __shfl_xor(r, 8);  r += __shfl_xor(r, 16); r += __shfl_xor(r, 32);
        if ((t & 63) == 0) red2[wid] = r;
    }
    __syncthreads();
    const float var = (red2[0] + red2[1]) * (1.0f / CC);

    const float nrm = dc * rsqrtf(var + 1e-5f) * gamma[t] + beta[t];
    mask_ch[b*CC + t] = 1.0f / (1.0f + __expf(-nrm));

    float wacc = 0.f;
    #pragma unroll
    for (int d = 0; d < CH; ++d) wacc += wv_sp[t*CH + d] * qsp[d];
    wf[b*CC + t] = wacc;
}

// ---------------- Pass 2: streaming output ----------------
// out[b,n,c] = x[b,n,c] * (mask_ch[b,c] + sigmoid(x_row . wf[b,:]))
// 6 rows in flight per 32-lane slot; nt stores protect L3-resident x.
__global__ __launch_bounds__(256, 6) void psa_pass2(
    const float* __restrict__ x, const float* __restrict__ mask_ch,
    const float* __restrict__ wf, float* __restrict__ out)
{
    const int b    = blockIdx.x / BPB;
    const int blk  = blockIdx.x % BPB;
    const int tid  = threadIdx.x;
    const int l32  = tid & 31;
    const int slot = tid >> 5;

    const f4 m4 = reinterpret_cast<const f4*>(mask_ch + b*CC)[l32];
    const f4 w4 = reinterpret_cast<const f4*>(wf + b*CC)[l32];

    const float* xb = x   + (size_t)b * (size_t)(HWN * CC);
    float*       ob = out + (size_t)b * (size_t)(HWN * CC);
    const int row0 = blk * ROWS;

    // ROWS=192 = 4 iterations of 48-row stride, 6 rows in flight per slot
    for (int i = slot; i < ROWS; i += 48) {
        const size_t off0 = (size_t)(row0 + i)      * CC;
        const size_t off1 = (size_t)(row0 + i + 8)  * CC;
        const size_t off2 = (size_t)(row0 + i + 16) * CC;
        const size_t off3 = (size_t)(row0 + i + 24) * CC;
        const size_t off4 = (size_t)(row0 + i + 32) * CC;
        const size_t off5 = (size_t)(row0 + i + 40) * CC;
        const f4 x0 = reinterpret_cast<const f4*>(xb + off0)[l32];
        const f4 x1 = reinterpret_cast<const f4*>(xb + off1)[l32];
        const f4 x2 = reinterpret_cast<const f4*>(xb + off2)[l32];
        const f4 x3 = reinterpret_cast<const f4*>(xb + off3)[l32];
        const f4 x4 = reinterpret_cast<const f4*>(xb + off4)[l32];
        const f4 x5 = reinterpret_cast<const f4*>(xb + off5)[l32];
        float p0 = x0.x*w4.x + x0.y*w4.y + x0.z*w4.z + x0.w*w4.w;
        float p1 = x1.x*w4.x + x1.y*w4.y + x1.z*w4.z + x1.w*w4.w;
        float p2 = x2.x*w4.x + x2.y*w4.y + x2.z*w4.z + x2.w*w4.w;
        float p3 = x3.x*w4.x + x3.y*w4.y + x3.z*w4.z + x3.w*w4.w;
        float p4 = x4.x*w4.x + x4.y*w4.y + x4.z*w4.z + x4.w*w4.w;
        float p5 = x5.x*w4.x + x5.y*w4.y + x5.z*w4.z + x5.w*w4.w;
        p0 += __shfl_xor(p0, 1);  p1 += __shfl_xor(p1, 1);  p2 += __shfl_xor(p2, 1);
        p3 += __shfl_xor(p3, 1);  p4 += __shfl_xor(p4, 1);  p5 += __shfl_xor(p5, 1);
        p0 += __shfl_xor(p0, 2);  p1 += __shfl_xor(p1, 2);  p2 += __shfl_xor(p2, 2);
        p3 += __shfl_xor(p3, 2);  p4 += __shfl_xor(p4, 2);  p5 += __shfl_xor(p5, 2);
        p0 += __shfl_xor(p0, 4);  p1 += __shfl_xor(p1, 4);  p2 += __shfl_xor(p2, 4);
        p3 += __shfl_xor(p3, 4);  p4 += __shfl_xor(p4, 4);  p5 += __shfl_xor(p5, 4);
        p0 += __shfl_xor(p0, 8);  p1 += __shfl_xor(p1, 8);  p2 += __shfl_xor(p2, 8);
        p3 += __shfl_xor(p3, 8);  p4 += __shfl_xor(p4, 8);  p5 += __shfl_xor(p5, 8);
        p0 += __shfl_xor(p0, 16); p1 += __shfl_xor(p1, 16); p2 += __shfl_xor(p2, 16);
        p3 += __shfl_xor(p3, 16); p4 += __shfl_xor(p4, 16); p5 += __shfl_xor(p5, 16);
        const float g0 = 1.0f / (1.0f + __expf(-p0));
        const float g1 = 1.0f / (1.0f + __expf(-p1));
        const float g2 = 1.0f / (1.0f + __expf(-p2));
        const float g3 = 1.0f / (1.0f + __expf(-p3));
        const float g4 = 1.0f / (1.0f + __expf(-p4));
        const float g5 = 1.0f / (1.0f + __expf(-p5));
        f4 o0, o1, o2, o3, o4, o5;
        o0.x = x0.x*(m4.x+g0); o0.y = x0.y*(m4.y+g0); o0.z = x0.z*(m4.z+g0); o0.w = x0.w*(m4.w+g0);
        o1.x = x1.x*(m4.x+g1); o1.y = x1.y*(m4.y+g1); o1.z = x1.z*(m4.z+g1); o1.w = x1.w*(m4.w+g1);
        o2.x = x2.x*(m4.x+g2); o2.y = x2.y*(m4.y+g2); o2.z = x2.z*(m4.z+g2); o2.w = x2.w*(m4.w+g2);
        o3.x = x3.x*(m4.x+g3); o3.y = x3.y*(m4.y+g3); o3.z = x3.z*(m4.z+g3); o3.w = x3.w*(m4.w+g3);
        o4.x = x4.x*(m4.x+g4); o4.y = x4.y*(m4.y+g4); o4.z = x4.z*(m4.z+g4); o4.w = x4.w*(m4.w+g4);
        o5.x = x5.x*(m4.x+g5); o5.y = x5.y*(m4.y+g5); o5.z = x5.z*(m4.z+g5); o5.w = x5.w*(m4.w+g5);
        // non-temporal: keep the out stream from evicting x in cache (R8 A/B: -20us)
        __builtin_nontemporal_store(o0, reinterpret_cast<f4*>(ob + off0) + l32);
        __builtin_nontemporal_store(o1, reinterpret_cast<f4*>(ob + off1) + l32);
        __builtin_nontemporal_store(o2, reinterpret_cast<f4*>(ob + off2) + l32);
        __builtin_nontemporal_store(o3, reinterpret_cast<f4*>(ob + off3) + l32);
        __builtin_nontemporal_store(o4, reinterpret_cast<f4*>(ob + off4) + l32);
        __builtin_nontemporal_store(o5, reinterpret_cast<f4*>(ob + off5) + l32);
    }
}

extern "C" void kernel_launch(void* const* d_in, const int* in_sizes, int n_in,
                              void* d_out, int out_size, void* d_ws, size_t ws_size,
                              hipStream_t stream) {
    const float* x     = (const float*)d_in[0];
    const float* wq_ch = (const float*)d_in[1];
    const float* wv_ch = (const float*)d_in[2];
    const float* w_ch  = (const float*)d_in[3];
    const float* gamma = (const float*)d_in[4];
    const float* beta  = (const float*)d_in[5];
    const float* wq_sp = (const float*)d_in[6];
    const float* wv_sp = (const float*)d_in[7];
    float* out = (float*)d_out;

    // workspace (floats): pS[32*64*128] | pX[32*64*128] | pZ[32*64] | mask[32*128] | wf[32*128]
    float* ws   = (float*)d_ws;
    float* pS   = ws;
    float* pX   = pS + (size_t)BSZ*BPB*CC;
    float* pZ   = pX + (size_t)BSZ*BPB*CC;
    float* mask = pZ + BSZ*BPB;
    float* wf   = mask + BSZ*CC;

    psa_pass1<<<BSZ*BPB, 256, 0, stream>>>(x, wq_ch, pS, pX, pZ);
    psa_mid  <<<BSZ,     128, 0, stream>>>(pS, pX, pZ, wv_ch, w_ch, gamma, beta,
                                           wq_sp, wv_sp, mask, wf);
    psa_pass2<<<BSZ*BPB, 256, 0, stream>>>(x, mask, wf, out);
}